// Round 1
// 116.896 us; speedup vs baseline: 1.0486x; 1.0486x over previous
//
#include <hip/hip_runtime.h>
#include <hip/hip_fp16.h>
#include <math.h>

#define BATCH 32
#define NPIX 160
#define LDIM 128
#define OUT_SZ 150        // 160 - 11 + 1

#define THREADS 512
// one fused block per (b, c, tile): 32*3*19 = 1824 work blocks + 1 KLD block
#define N_BLOCKS 1825
// LDS carve (float units):
//   HXY stage: 18*160 half2 = 2880 fl-equiv (11.5 KB)
//   scratch region at 2880: stft RD (6080 half2) OR ssim V planes (5*1296 fl)
#define SCRATCH_OFF 2880
#define VSTRIDE 1296
#define SMEM_FLOATS 9360   // 37.4 KB -> 4 blocks/CU

// e^{-i*2pi*k/12}; entries 0 / ±0.5 / ±0.866 / ±1 -> FMAs fold at compile time
__device__ constexpr float TWC[12] = { 1.f, 0.86602540f, 0.5f, 0.f, -0.5f, -0.86602540f,
                                      -1.f,-0.86602540f,-0.5f, 0.f,  0.5f,  0.86602540f};
__device__ constexpr float TWS[12] = { 0.f,-0.5f,-0.86602540f,-1.f,-0.86602540f,-0.5f,
                                       0.f, 0.5f, 0.86602540f, 1.f, 0.86602540f, 0.5f};

__device__ constexpr float GW[11] = {0.00102838f, 0.00759876f, 0.03600076f, 0.10936070f,
                                     0.21300554f, 0.26601172f, 0.21300554f, 0.10936070f,
                                     0.03600076f, 0.00759876f, 0.00102838f};

// minimax atan poly, max err ~1e-6 rad (validated R7/R9-R14, absmax 0.0)
// div -> v_rcp_f32 (adds ~1ulp, far below poly error)
__device__ __forceinline__ float fast_atan2f(float y, float x) {
    float ax = fabsf(x), ay = fabsf(y);
    float mx = fmaxf(ax, ay), mn = fminf(ax, ay);
    float z = mn * __builtin_amdgcn_rcpf(mx);
    float z2 = z * z;
    float p = fmaf(z2, -0.01172120f, 0.05265332f);
    p = fmaf(z2, p, -0.11643287f);
    p = fmaf(z2, p, 0.19354346f);
    p = fmaf(z2, p, -0.33262347f);
    p = fmaf(z2, p, 0.99997726f);
    p = p * z;
    if (ay > ax) p = 1.57079632679489662f - p;
    if (x < 0.f) p = 3.14159265358979323f - p;
    return (y < 0.f) ? -p : p;
}

// extract channel C of 4 consecutive NHWC pixels held in 3 float4s (wave-uniform c)
__device__ __forceinline__ float4 extract_c(float4 f0, float4 f1, float4 f2, int c) {
    if (c == 0) return make_float4(f0.x, f0.w, f1.z, f2.y);
    if (c == 1) return make_float4(f0.y, f1.x, f1.w, f2.z);
    return make_float4(f0.z, f1.y, f2.x, f2.w);
}

__global__ __launch_bounds__(THREADS) void work_kernel(const float* __restrict__ xin,
                                                       const float* __restrict__ xout,
                                                       const float* __restrict__ mean,
                                                       const float* __restrict__ logvar,
                                                       float* __restrict__ out) {
    __shared__ __align__(16) float SMEM[SMEM_FLOATS];
    __shared__ float sm8[8];
    const int tid = threadIdx.x;
    const int gid = blockIdx.x;
    float acc = 0.f;

    if (gid == 1824) {
        // ---- KLD block ----
        float a = 0.f;
        for (int i = tid; i < BATCH * LDIM; i += THREADS) {
            float m = mean[i], lv = logvar[i];
            a += -0.5f * (1.f + lv - expf(lv) - m * m) * (1.f / 32.f);
        }
        #pragma unroll
        for (int o = 32; o > 0; o >>= 1) a += __shfl_down(a, o, 64);
        if ((tid & 63) == 0) sm8[tid >> 6] = a;
        __syncthreads();
        if (tid == 0) {
            float s = sm8[0];
            #pragma unroll
            for (int i = 1; i < 8; ++i) s += sm8[i];
            atomicAdd(out, s);
        }
        return;
    }

    // fused work block: (b, c, tile); tile covers ssim rows 8t..8t+17, stft rows 8t..8t+15
    int b    = gid / 57;
    int rem  = gid % 57;
    int c    = rem / 19;
    int tile = rem % 19;
    int r0 = tile * 8;
    __half2* HXY = (__half2*)SMEM;                   // [rr 0..17][col] = (x, y)
    __half2* RD  = (__half2*)(SMEM + SCRATCH_OFF);   // stft scratch [r][vv][pc][img] (img innermost)

    // ---- stage: 720 tasks (rr, colq); NHWC both imgs, extract c, pack half2 ----
    for (int t = tid; t < 720; t += THREADS) {
        int rr = t / 40;
        int cq = t % 40;
        int row = r0 + rr;
        float4 xa = make_float4(0.f, 0.f, 0.f, 0.f);
        float4 xb = make_float4(0.f, 0.f, 0.f, 0.f);
        if (row < NPIX) {
            size_t off = ((size_t)(b * 160 + row) * 160 + cq * 4) * 3;
            const float4* qa = (const float4*)(xin + off);
            const float4* qb = (const float4*)(xout + off);
            float4 a0 = qa[0], a1 = qa[1], a2 = qa[2];
            float4 b0 = qb[0], b1 = qb[1], b2 = qb[2];
            xa = extract_c(a0, a1, a2, c);
            xb = extract_c(b0, b1, b2, c);
        }
        __half2 h[4] __attribute__((aligned(16)));
        h[0] = __floats2half2_rn(xa.x, xb.x);
        h[1] = __floats2half2_rn(xa.y, xb.y);
        h[2] = __floats2half2_rn(xa.z, xb.z);
        h[3] = __floats2half2_rn(xa.w, xb.w);
        *(float4*)&HXY[rr * 160 + cq * 4] = *(float4*)h;
    }
    __syncthreads();

    // ---- stft phase A: 608 tasks (r 0..15, pc); both images; real-input symmetry ----
    // RD layout img-innermost: one float2 (both imgs' half2) write per vv -> b64 traffic
    for (int t = tid; t < 608; t += THREADS) {
        int pc = t % 38;
        int r  = t / 38;
        float4 raw[3];
        raw[0] = *(const float4*)&HXY[r * 160 + pc * 4];
        raw[1] = *(const float4*)&HXY[r * 160 + pc * 4 + 4];
        raw[2] = *(const float4*)&HXY[r * 160 + pc * 4 + 8];
        const __half2* hp = (const __half2*)raw;
        float xa[12], xb[12];
        #pragma unroll
        for (int j = 0; j < 12; ++j) {
            float2 xy = __half22float2(hp[j]);
            xa[j] = xy.x; xb[j] = xy.y;
        }
        float evA[5] = {xa[1]+xa[11], xa[2]+xa[10], xa[3]+xa[9], xa[4]+xa[8], xa[5]+xa[7]};
        float ovA[5] = {xa[1]-xa[11], xa[2]-xa[10], xa[3]-xa[9], xa[4]-xa[8], xa[5]-xa[7]};
        float evB[5] = {xb[1]+xb[11], xb[2]+xb[10], xb[3]+xb[9], xb[4]+xb[8], xb[5]+xb[7]};
        float ovB[5] = {xb[1]-xb[11], xb[2]-xb[10], xb[3]-xb[9], xb[4]-xb[8], xb[5]-xb[7]};
        #pragma unroll
        for (int vv = 0; vv < 5; ++vv) {
            int v = vv + 1;
            float reA = xa[0] + ((v & 1) ? -xa[6] : xa[6]);
            float reB = xb[0] + ((v & 1) ? -xb[6] : xb[6]);
            float imA = 0.f, imB = 0.f;
            #pragma unroll
            for (int j = 1; j <= 5; ++j) {
                int kk = (v * j) % 12;           // compile-time
                reA = fmaf(evA[j-1], TWC[kk], reA);
                imA = fmaf(ovA[j-1], TWS[kk], imA);
                reB = fmaf(evB[j-1], TWC[kk], reB);
                imB = fmaf(ovB[j-1], TWS[kk], imB);
            }
            __half2 w2[2] __attribute__((aligned(8)));
            w2[0] = __floats2half2_rn(reA, imA);
            w2[1] = __floats2half2_rn(reB, imB);
            *(float2*)&RD[(((r * 5 + vv) * 38) + pc) * 2] = *(float2*)w2;
        }
    }
    __syncthreads();

    // ---- stft phase B: 380 tasks (g, vv, pc); half-period fold, all 5 u per task ----
    if (tid < 380) {
        int pc = tid % 38;
        int vv = (tid / 38) % 5;
        int g  = tid / 190;
        float FR0[5] = {0,0,0,0,0}, FI0[5] = {0,0,0,0,0};
        float FR1[5] = {0,0,0,0,0}, FI1[5] = {0,0,0,0,0};
        #pragma unroll
        for (int i = 0; i < 6; ++i) {
            int rlo = 4 * g + i, rhi = rlo + 6;
            __half2 p0[2] __attribute__((aligned(8)));
            __half2 p6[2] __attribute__((aligned(8)));
            *(float2*)p0 = *(const float2*)&RD[(((rlo * 5 + vv) * 38) + pc) * 2];
            *(float2*)p6 = *(const float2*)&RD[(((rhi * 5 + vv) * 38) + pc) * 2];
            float2 a0 = __half22float2(p0[0]);
            float2 b0 = __half22float2(p0[1]);
            float2 a6 = __half22float2(p6[0]);
            float2 b6 = __half22float2(p6[1]);
            float spR0 = a0.x + a6.x, spI0 = a0.y + a6.y;
            float smR0 = a0.x - a6.x, smI0 = a0.y - a6.y;
            float spR1 = b0.x + b6.x, spI1 = b0.y + b6.y;
            float smR1 = b0.x - b6.x, smI1 = b0.y - b6.y;
            #pragma unroll
            for (int uu = 0; uu < 5; ++uu) {
                int u = uu + 1;
                int kk = (u * i) % 12;               // compile-time twiddle
                float cu = TWC[kk], su = TWS[kk];
                float sR0 = (u & 1) ? smR0 : spR0, sI0 = (u & 1) ? smI0 : spI0;
                float sR1 = (u & 1) ? smR1 : spR1, sI1 = (u & 1) ? smI1 : spI1;
                FR0[uu] = fmaf(cu, sR0, fmaf(-su, sI0, FR0[uu]));
                FI0[uu] = fmaf(cu, sI0, fmaf( su, sR0, FI0[uu]));
                FR1[uu] = fmaf(cu, sR1, fmaf(-su, sI1, FR1[uu]));
                FI1[uu] = fmaf(cu, sI1, fmaf( su, sR1, FI1[uu]));
            }
        }
        float sacc = 0.f;
        #pragma unroll
        for (int uu = 0; uu < 5; ++uu) {
            float aI = fast_atan2f(FI0[uu], FR0[uu] + 1e-8f);
            float aO = fast_atan2f(FI1[uu], FR1[uu] + 1e-8f);
            float mI = __builtin_amdgcn_sqrtf(fmaf(FR0[uu], FR0[uu], FI0[uu] * FI0[uu]));
            float mO = __builtin_amdgcn_sqrtf(fmaf(FR1[uu], FR1[uu], FI1[uu] * FI1[uu]));
            float ff = (float)((uu + 1) * (vv + 1)) * 0.04f;
            sacc += ff * (fabsf(aO - aI) + fabsf(mO - mI));
        }
        acc += sacc * (1e-4f / 32.f);
    }
    __syncthreads();   // RD dead; V planes reuse the scratch region

    // ---- ssim phase V: vertical 11-tap, 320 tasks; writes V planes over scratch ----
    // tx/ty reuse: 8 VALU ops per (tap, pixel) instead of 10-11
    for (int t = tid; t < 320; t += THREADS) {
        int orow = t / 40;
        int cbase = (t % 40) * 4;
        float ax[4] = {0,0,0,0}, ay[4] = {0,0,0,0};
        float axx[4] = {0,0,0,0}, ayy[4] = {0,0,0,0}, axy[4] = {0,0,0,0};
        #pragma unroll
        for (int kk = 0; kk < 11; ++kk) {
            float4 raw = *(const float4*)&HXY[(orow + kk) * 160 + cbase];
            const __half2* hp = (const __half2*)&raw;
            float wg = GW[kk];
            #pragma unroll
            for (int o = 0; o < 4; ++o) {
                float2 xy = __half22float2(hp[o]);
                float tx = wg * xy.x, ty = wg * xy.y;
                ax[o]  += tx;
                ay[o]  += ty;
                axx[o] = fmaf(tx, xy.x, axx[o]);
                ayy[o] = fmaf(ty, xy.y, ayy[o]);
                axy[o] = fmaf(tx, xy.y, axy[o]);
            }
        }
        int base = SCRATCH_OFF + orow * 160 + cbase;
        *(float4*)&SMEM[base + 0 * VSTRIDE] = make_float4(ax[0],  ax[1],  ax[2],  ax[3]);
        *(float4*)&SMEM[base + 1 * VSTRIDE] = make_float4(ay[0],  ay[1],  ay[2],  ay[3]);
        *(float4*)&SMEM[base + 2 * VSTRIDE] = make_float4(axx[0], axx[1], axx[2], axx[3]);
        *(float4*)&SMEM[base + 3 * VSTRIDE] = make_float4(ayy[0], ayy[1], ayy[2], ayy[3]);
        *(float4*)&SMEM[base + 4 * VSTRIDE] = make_float4(axy[0], axy[1], axy[2], axy[3]);
    }
    __syncthreads();

    // ---- ssim phase H: 600 tasks (8 orows x 75 col-pairs), stride-2 windows ----
    // b64 loads (oc always even -> aligned); rcp for lum/cs denominators
    {
        float hacc = 0.f;
        for (int t = tid; t < 600; t += THREADS) {
            int orow = t / 75;
            int oc = (t % 75) * 2;
            float st[5][2];
            #pragma unroll
            for (int p = 0; p < 5; ++p) {
                const float* rowp = &SMEM[SCRATCH_OFF + p * VSTRIDE + orow * 160 + oc];
                float vals[12];
                #pragma unroll
                for (int q = 0; q < 6; ++q) {
                    float2 v2 = *(const float2*)&rowp[2 * q];
                    vals[2 * q]     = v2.x;
                    vals[2 * q + 1] = v2.y;
                }
                float s0 = 0.f, s1 = 0.f;
                #pragma unroll
                for (int kk = 0; kk < 11; ++kk) {
                    s0 += GW[kk] * vals[kk];
                    s1 += GW[kk] * vals[kk + 1];
                }
                st[p][0] = s0; st[p][1] = s1;
            }
            const float c1 = 1e-4f, c2 = 9e-4f;
            if (r0 + orow < OUT_SZ) {
                #pragma unroll
                for (int o = 0; o < 2; ++o) {
                    float mx = st[0][o], my = st[1][o];
                    float vx = st[2][o] - mx * mx;
                    float vy = st[3][o] - my * my;
                    float cv = st[4][o] - mx * my;
                    float lum = (2.f * mx * my + c1) *
                                __builtin_amdgcn_rcpf(fmaf(mx, mx, my * my) + c1);
                    float cs  = (2.f * cv + c2) *
                                __builtin_amdgcn_rcpf(vx + vy + c2);
                    hacc += lum * cs;
                }
            }
        }
        acc += hacc * (1.f / (32.f * 150.f * 150.f * 3.f));
    }

    // ---- block reduce (8 waves) -> one device-scope atomic per block ----
    #pragma unroll
    for (int o = 32; o > 0; o >>= 1) acc += __shfl_down(acc, o, 64);
    if ((tid & 63) == 0) sm8[tid >> 6] = acc;
    __syncthreads();
    if (tid == 0) {
        float s = sm8[0];
        #pragma unroll
        for (int i = 1; i < 8; ++i) s += sm8[i];
        atomicAdd(out, s);
    }
}

extern "C" void kernel_launch(void* const* d_in, const int* in_sizes, int n_in,
                              void* d_out, int out_size, void* d_ws, size_t ws_size,
                              hipStream_t stream) {
    const float* mean   = (const float*)d_in[0];
    const float* logvar = (const float*)d_in[1];
    const float* xin    = (const float*)d_in[2];
    const float* xout   = (const float*)d_in[3];
    float* out = (float*)d_out;

    hipMemsetAsync(out, 0, sizeof(float), stream);   // graph-capturable memset node
    work_kernel<<<N_BLOCKS, THREADS, 0, stream>>>(xin, xout, mean, logvar, out);
}

// Round 3
// 114.037 us; speedup vs baseline: 1.0749x; 1.0251x over previous
//
#include <hip/hip_runtime.h>
#include <hip/hip_fp16.h>
#include <math.h>

#define BATCH 32
#define NPIX 160
#define LDIM 128
#define OUT_SZ 150        // 160 - 11 + 1

#define THREADS 512
// one fused block per (b, c, tile): 32*3*19 = 1824 work blocks + 1 KLD block
#define N_BLOCKS 1825
// LDS carve (float units; NOTE one __half2 = 4 B = ONE float slot):
//   HXY  [0,2880):       half2[18][160] staged pixels (x, y)
//   RD   [2880,8960):    stft row-DFT scratch, 16*5*38*2 half2 = 6080 slots
//   VPMU [8960,10272):   half2[8][164] = (mu_x, mu_y)
//   VPVV [10272,11584):  half2[8][164] = (E[xx], E[yy])
//   VPXY [11584,12896):  float[8][164] = E[xy]
// all regions disjoint -> dependency graph is stage -> {A,V} -> {B,H}: 3 barriers
// (R2's NaN was VP* carved inside RD's real extent; fixed here.)
#define RD_OFF   2880
#define VPMU_OFF 8960
#define VPVV_OFF 10272
#define VPXY_OFF 11584
#define VROWSTR  164
#define SMEM_FLOATS 12896  // 51.6 KB -> 3 blocks/CU (<= 53.3 KB bound)

// e^{-i*2pi*k/12}; entries 0 / ±0.5 / ±0.866 / ±1 -> FMAs fold at compile time
__device__ constexpr float TWC[12] = { 1.f, 0.86602540f, 0.5f, 0.f, -0.5f, -0.86602540f,
                                      -1.f,-0.86602540f,-0.5f, 0.f,  0.5f,  0.86602540f};
__device__ constexpr float TWS[12] = { 0.f,-0.5f,-0.86602540f,-1.f,-0.86602540f,-0.5f,
                                       0.f, 0.5f, 0.86602540f, 1.f, 0.86602540f, 0.5f};

__device__ constexpr float GW[11] = {0.00102838f, 0.00759876f, 0.03600076f, 0.10936070f,
                                     0.21300554f, 0.26601172f, 0.21300554f, 0.10936070f,
                                     0.03600076f, 0.00759876f, 0.00102838f};

// minimax atan poly, max err ~1e-6 rad (validated R7/R9-R14, absmax 0.0)
// div -> v_rcp_f32 (adds ~1ulp, far below poly error)
__device__ __forceinline__ float fast_atan2f(float y, float x) {
    float ax = fabsf(x), ay = fabsf(y);
    float mx = fmaxf(ax, ay), mn = fminf(ax, ay);
    float z = mn * __builtin_amdgcn_rcpf(mx);
    float z2 = z * z;
    float p = fmaf(z2, -0.01172120f, 0.05265332f);
    p = fmaf(z2, p, -0.11643287f);
    p = fmaf(z2, p, 0.19354346f);
    p = fmaf(z2, p, -0.33262347f);
    p = fmaf(z2, p, 0.99997726f);
    p = p * z;
    if (ay > ax) p = 1.57079632679489662f - p;
    if (x < 0.f) p = 3.14159265358979323f - p;
    return (y < 0.f) ? -p : p;
}

// extract channel C of 4 consecutive NHWC pixels held in 3 float4s (wave-uniform c)
__device__ __forceinline__ float4 extract_c(float4 f0, float4 f1, float4 f2, int c) {
    if (c == 0) return make_float4(f0.x, f0.w, f1.z, f2.y);
    if (c == 1) return make_float4(f0.y, f1.x, f1.w, f2.z);
    return make_float4(f0.z, f1.y, f2.x, f2.w);
}

__global__ __launch_bounds__(THREADS) void work_kernel(const float* __restrict__ xin,
                                                       const float* __restrict__ xout,
                                                       const float* __restrict__ mean,
                                                       const float* __restrict__ logvar,
                                                       float* __restrict__ out) {
    __shared__ __align__(16) float SMEM[SMEM_FLOATS];
    __shared__ float sm8[8];
    const int tid = threadIdx.x;
    const int gid = blockIdx.x;
    float acc = 0.f;

    if (gid == 1824) {
        // ---- KLD block ----
        float a = 0.f;
        for (int i = tid; i < BATCH * LDIM; i += THREADS) {
            float m = mean[i], lv = logvar[i];
            a += -0.5f * (1.f + lv - expf(lv) - m * m) * (1.f / 32.f);
        }
        #pragma unroll
        for (int o = 32; o > 0; o >>= 1) a += __shfl_down(a, o, 64);
        if ((tid & 63) == 0) sm8[tid >> 6] = a;
        __syncthreads();
        if (tid == 0) {
            float s = sm8[0];
            #pragma unroll
            for (int i = 1; i < 8; ++i) s += sm8[i];
            atomicAdd(out, s);
        }
        return;
    }

    // fused work block: (b, c, tile); tile covers ssim rows 8t..8t+17, stft rows 8t..8t+15
    int b    = gid / 57;
    int rem  = gid % 57;
    int c    = rem / 19;
    int tile = rem % 19;
    int r0 = tile * 8;
    __half2* HXY = (__half2*)SMEM;                 // [rr 0..17][col] = (x, y)
    __half2* RD  = (__half2*)(SMEM + RD_OFF);      // stft scratch [r][vv][pc][img]

    // ---- stage: 720 tasks (rr, colq); NHWC both imgs, extract c, pack half2 ----
    for (int t = tid; t < 720; t += THREADS) {
        int rr = t / 40;
        int cq = t % 40;
        int row = r0 + rr;
        float4 xa = make_float4(0.f, 0.f, 0.f, 0.f);
        float4 xb = make_float4(0.f, 0.f, 0.f, 0.f);
        if (row < NPIX) {
            size_t off = ((size_t)(b * 160 + row) * 160 + cq * 4) * 3;
            const float4* qa = (const float4*)(xin + off);
            const float4* qb = (const float4*)(xout + off);
            float4 a0 = qa[0], a1 = qa[1], a2 = qa[2];
            float4 b0 = qb[0], b1 = qb[1], b2 = qb[2];
            xa = extract_c(a0, a1, a2, c);
            xb = extract_c(b0, b1, b2, c);
        }
        __half2 h[4] __attribute__((aligned(16)));
        h[0] = __floats2half2_rn(xa.x, xb.x);
        h[1] = __floats2half2_rn(xa.y, xb.y);
        h[2] = __floats2half2_rn(xa.z, xb.z);
        h[3] = __floats2half2_rn(xa.w, xb.w);
        *(float4*)&HXY[rr * 160 + cq * 4] = *(float4*)h;
    }
    __syncthreads();

    // ================= pool 2: stft row-DFT (A) + ssim vertical (V) =================
    // both read HXY only; A writes RD, V writes VP* (disjoint) -> no barrier between

    // ---- stft phase A: 608 tasks (r 0..15, pc); both images; real-input symmetry ----
    for (int t = tid; t < 608; t += THREADS) {
        int pc = t % 38;
        int r  = t / 38;
        float4 raw[3];
        raw[0] = *(const float4*)&HXY[r * 160 + pc * 4];
        raw[1] = *(const float4*)&HXY[r * 160 + pc * 4 + 4];
        raw[2] = *(const float4*)&HXY[r * 160 + pc * 4 + 8];
        const __half2* hp = (const __half2*)raw;
        float xa[12], xb[12];
        #pragma unroll
        for (int j = 0; j < 12; ++j) {
            float2 xy = __half22float2(hp[j]);
            xa[j] = xy.x; xb[j] = xy.y;
        }
        float evA[5] = {xa[1]+xa[11], xa[2]+xa[10], xa[3]+xa[9], xa[4]+xa[8], xa[5]+xa[7]};
        float ovA[5] = {xa[1]-xa[11], xa[2]-xa[10], xa[3]-xa[9], xa[4]-xa[8], xa[5]-xa[7]};
        float evB[5] = {xb[1]+xb[11], xb[2]+xb[10], xb[3]+xb[9], xb[4]+xb[8], xb[5]+xb[7]};
        float ovB[5] = {xb[1]-xb[11], xb[2]-xb[10], xb[3]-xb[9], xb[4]-xb[8], xb[5]-xb[7]};
        #pragma unroll
        for (int vv = 0; vv < 5; ++vv) {
            int v = vv + 1;
            float reA = xa[0] + ((v & 1) ? -xa[6] : xa[6]);
            float reB = xb[0] + ((v & 1) ? -xb[6] : xb[6]);
            float imA = 0.f, imB = 0.f;
            #pragma unroll
            for (int j = 1; j <= 5; ++j) {
                int kk = (v * j) % 12;           // compile-time
                reA = fmaf(evA[j-1], TWC[kk], reA);
                imA = fmaf(ovA[j-1], TWS[kk], imA);
                reB = fmaf(evB[j-1], TWC[kk], reB);
                imB = fmaf(ovB[j-1], TWS[kk], imB);
            }
            __half2 w2[2] __attribute__((aligned(8)));
            w2[0] = __floats2half2_rn(reA, imA);
            w2[1] = __floats2half2_rn(reB, imB);
            *(float2*)&RD[(((r * 5 + vv) * 38) + pc) * 2] = *(float2*)w2;
        }
    }

    // ---- ssim phase V: vertical 11-tap, 320 tasks (reversed index: balance vs A) ----
    // fp32 accumulate from HXY; pack (mu) and (E[xx],E[yy]) planes to half2
    {
        int vt = (THREADS - 1) - tid;
        if (vt < 320) {
            int orow = vt / 40;
            int cbase = (vt % 40) * 4;
            float ax[4] = {0,0,0,0}, ay[4] = {0,0,0,0};
            float axx[4] = {0,0,0,0}, ayy[4] = {0,0,0,0}, axy[4] = {0,0,0,0};
            #pragma unroll
            for (int kk = 0; kk < 11; ++kk) {
                float4 raw = *(const float4*)&HXY[(orow + kk) * 160 + cbase];
                const __half2* hp = (const __half2*)&raw;
                float wg = GW[kk];
                #pragma unroll
                for (int o = 0; o < 4; ++o) {
                    float2 xy = __half22float2(hp[o]);
                    float tx = wg * xy.x, ty = wg * xy.y;
                    ax[o]  += tx;
                    ay[o]  += ty;
                    axx[o] = fmaf(tx, xy.x, axx[o]);
                    ayy[o] = fmaf(ty, xy.y, ayy[o]);
                    axy[o] = fmaf(tx, xy.y, axy[o]);
                }
            }
            __half2 pm[4] __attribute__((aligned(16)));
            __half2 pv[4] __attribute__((aligned(16)));
            #pragma unroll
            for (int o = 0; o < 4; ++o) {
                pm[o] = __floats2half2_rn(ax[o],  ay[o]);
                pv[o] = __floats2half2_rn(axx[o], ayy[o]);
            }
            int base = orow * VROWSTR + cbase;
            *(float4*)&SMEM[VPMU_OFF + base] = *(float4*)pm;
            *(float4*)&SMEM[VPVV_OFF + base] = *(float4*)pv;
            *(float4*)&SMEM[VPXY_OFF + base] = make_float4(axy[0], axy[1], axy[2], axy[3]);
        }
    }
    __syncthreads();

    // ================= pool 3: stft col-DFT+loss (B) + ssim horizontal (H) ==========
    // B reads RD, H reads VP* -- disjoint, read-only -> no barrier between

    // ---- stft phase B: 380 tasks (g, vv, pc); half-period fold, all 5 u per task ----
    if (tid < 380) {
        int pc = tid % 38;
        int vv = (tid / 38) % 5;
        int g  = tid / 190;
        float FR0[5] = {0,0,0,0,0}, FI0[5] = {0,0,0,0,0};
        float FR1[5] = {0,0,0,0,0}, FI1[5] = {0,0,0,0,0};
        #pragma unroll
        for (int i = 0; i < 6; ++i) {
            int rlo = 4 * g + i, rhi = rlo + 6;
            __half2 p0[2] __attribute__((aligned(8)));
            __half2 p6[2] __attribute__((aligned(8)));
            *(float2*)p0 = *(const float2*)&RD[(((rlo * 5 + vv) * 38) + pc) * 2];
            *(float2*)p6 = *(const float2*)&RD[(((rhi * 5 + vv) * 38) + pc) * 2];
            float2 a0 = __half22float2(p0[0]);
            float2 b0 = __half22float2(p0[1]);
            float2 a6 = __half22float2(p6[0]);
            float2 b6 = __half22float2(p6[1]);
            float spR0 = a0.x + a6.x, spI0 = a0.y + a6.y;
            float smR0 = a0.x - a6.x, smI0 = a0.y - a6.y;
            float spR1 = b0.x + b6.x, spI1 = b0.y + b6.y;
            float smR1 = b0.x - b6.x, smI1 = b0.y - b6.y;
            #pragma unroll
            for (int uu = 0; uu < 5; ++uu) {
                int u = uu + 1;
                int kk = (u * i) % 12;               // compile-time twiddle
                float cu = TWC[kk], su = TWS[kk];
                float sR0 = (u & 1) ? smR0 : spR0, sI0 = (u & 1) ? smI0 : spI0;
                float sR1 = (u & 1) ? smR1 : spR1, sI1 = (u & 1) ? smI1 : spI1;
                FR0[uu] = fmaf(cu, sR0, fmaf(-su, sI0, FR0[uu]));
                FI0[uu] = fmaf(cu, sI0, fmaf( su, sR0, FI0[uu]));
                FR1[uu] = fmaf(cu, sR1, fmaf(-su, sI1, FR1[uu]));
                FI1[uu] = fmaf(cu, sI1, fmaf( su, sR1, FI1[uu]));
            }
        }
        float sacc = 0.f;
        #pragma unroll
        for (int uu = 0; uu < 5; ++uu) {
            float aI = fast_atan2f(FI0[uu], FR0[uu] + 1e-8f);
            float aO = fast_atan2f(FI1[uu], FR1[uu] + 1e-8f);
            float mI = __builtin_amdgcn_sqrtf(fmaf(FR0[uu], FR0[uu], FI0[uu] * FI0[uu]));
            float mO = __builtin_amdgcn_sqrtf(fmaf(FR1[uu], FR1[uu], FI1[uu] * FI1[uu]));
            float ff = (float)((uu + 1) * (vv + 1)) * 0.04f;
            sacc += ff * (fabsf(aO - aI) + fabsf(mO - mI));
        }
        acc += sacc * (1e-4f / 32.f);
    }

    // ---- ssim phase H: 600 tasks (reversed index: B-less threads take extras) ----
    // planes streamed one at a time to keep live set small
    {
        float hacc = 0.f;
        for (int t = (THREADS - 1) - tid; t < 600; t += THREADS) {
            int orow = t / 75;
            int oc = (t % 75) * 2;
            int base = orow * VROWSTR + oc;
            float mx0, mx1, my0, my1, xx0, xx1, yy0, yy1, xy0, xy1;
            {   // mu plane (half2)
                float xs[12], ys[12];
                #pragma unroll
                for (int q = 0; q < 6; ++q) {
                    float2 m2 = *(const float2*)&SMEM[VPMU_OFF + base + 2 * q];
                    const __half2* mh = (const __half2*)&m2;
                    float2 a = __half22float2(mh[0]), bb = __half22float2(mh[1]);
                    xs[2*q] = a.x;  ys[2*q] = a.y;
                    xs[2*q+1] = bb.x; ys[2*q+1] = bb.y;
                }
                float s0=0.f, s1=0.f, s2=0.f, s3=0.f;
                #pragma unroll
                for (int kk = 0; kk < 11; ++kk) {
                    s0 = fmaf(GW[kk], xs[kk],   s0);
                    s1 = fmaf(GW[kk], xs[kk+1], s1);
                    s2 = fmaf(GW[kk], ys[kk],   s2);
                    s3 = fmaf(GW[kk], ys[kk+1], s3);
                }
                mx0 = s0; mx1 = s1; my0 = s2; my1 = s3;
            }
            {   // E[xx]/E[yy] plane (half2)
                float xs[12], ys[12];
                #pragma unroll
                for (int q = 0; q < 6; ++q) {
                    float2 v2 = *(const float2*)&SMEM[VPVV_OFF + base + 2 * q];
                    const __half2* vh = (const __half2*)&v2;
                    float2 a = __half22float2(vh[0]), bb = __half22float2(vh[1]);
                    xs[2*q] = a.x;  ys[2*q] = a.y;
                    xs[2*q+1] = bb.x; ys[2*q+1] = bb.y;
                }
                float s0=0.f, s1=0.f, s2=0.f, s3=0.f;
                #pragma unroll
                for (int kk = 0; kk < 11; ++kk) {
                    s0 = fmaf(GW[kk], xs[kk],   s0);
                    s1 = fmaf(GW[kk], xs[kk+1], s1);
                    s2 = fmaf(GW[kk], ys[kk],   s2);
                    s3 = fmaf(GW[kk], ys[kk+1], s3);
                }
                xx0 = s0; xx1 = s1; yy0 = s2; yy1 = s3;
            }
            {   // E[xy] plane (fp32)
                float zs[12];
                #pragma unroll
                for (int q = 0; q < 6; ++q) {
                    float2 y2 = *(const float2*)&SMEM[VPXY_OFF + base + 2 * q];
                    zs[2*q] = y2.x; zs[2*q+1] = y2.y;
                }
                float s0=0.f, s1=0.f;
                #pragma unroll
                for (int kk = 0; kk < 11; ++kk) {
                    s0 = fmaf(GW[kk], zs[kk],   s0);
                    s1 = fmaf(GW[kk], zs[kk+1], s1);
                }
                xy0 = s0; xy1 = s1;
            }
            if (r0 + orow < OUT_SZ) {
                const float c1 = 1e-4f, c2 = 9e-4f;
                #pragma unroll
                for (int o = 0; o < 2; ++o) {
                    float mx = o ? mx1 : mx0, my = o ? my1 : my0;
                    float ex = o ? xx1 : xx0, ey = o ? yy1 : yy0;
                    float cv = (o ? xy1 : xy0) - mx * my;
                    float vx = ex - mx * mx;
                    float vy = ey - my * my;
                    float lum = (2.f * mx * my + c1) *
                                __builtin_amdgcn_rcpf(fmaf(mx, mx, my * my) + c1);
                    float cs  = (2.f * cv + c2) *
                                __builtin_amdgcn_rcpf(vx + vy + c2);
                    hacc += lum * cs;
                }
            }
        }
        acc += hacc * (1.f / (32.f * 150.f * 150.f * 3.f));
    }

    // ---- block reduce (8 waves) -> one device-scope atomic per block ----
    #pragma unroll
    for (int o = 32; o > 0; o >>= 1) acc += __shfl_down(acc, o, 64);
    if ((tid & 63) == 0) sm8[tid >> 6] = acc;
    __syncthreads();
    if (tid == 0) {
        float s = sm8[0];
        #pragma unroll
        for (int i = 1; i < 8; ++i) s += sm8[i];
        atomicAdd(out, s);
    }
}

extern "C" void kernel_launch(void* const* d_in, const int* in_sizes, int n_in,
                              void* d_out, int out_size, void* d_ws, size_t ws_size,
                              hipStream_t stream) {
    const float* mean   = (const float*)d_in[0];
    const float* logvar = (const float*)d_in[1];
    const float* xin    = (const float*)d_in[2];
    const float* xout   = (const float*)d_in[3];
    float* out = (float*)d_out;

    hipMemsetAsync(out, 0, sizeof(float), stream);   // graph-capturable memset node
    work_kernel<<<N_BLOCKS, THREADS, 0, stream>>>(xin, xout, mean, logvar, out);
}

// Round 4
// 105.200 us; speedup vs baseline: 1.1651x; 1.0840x over previous
//
#include <hip/hip_runtime.h>
#include <hip/hip_fp16.h>
#include <math.h>

#define BATCH 32
#define NPIX 160
#define LDIM 128
#define OUT_SZ 150        // 160 - 11 + 1

#define THREADS 512
// one fused block per (b, c, tile): 32*3*19 = 1824 work blocks + 1 KLD block
#define N_BLOCKS 1825
// LDS carve (float units; one __half2 = 4 B = ONE float slot):
//   HXY  [0,2880):  half2[18][160] staged pixels (x=img_in, y=img_out)
//   SCRATCH [2880,8960): union region, sequential use:
//     stft RD:  16r * 5vv * 38pc * 2(re2,im2) half2 = 6080 slots  (phases A,B)
//     ssim VP:  VPMU half2[8][164] (mu_x,mu_y)      = 1312       (phases V,H)
//               VPVV half2[8][164] (E[xx],E[yy])    = 1312
//               VPXY float[8][164]  E[xy]           = 1312  (total 3936 <= 6080)
// 5-phase structure (R1): stage -> A -> B -> V -> H; V overwrites RD after B.
#define RD_OFF   2880
#define VPMU_OFF 2880
#define VPVV_OFF 4192
#define VPXY_OFF 5504
#define VROWSTR  164
#define SMEM_FLOATS 8960   // 35.8 KB -> 4 blocks/CU (32 waves = full slots)

// e^{-i*2pi*k/12}; entries 0 / ±0.5 / ±0.866 / ±1
__device__ constexpr float TWC[12] = { 1.f, 0.86602540f, 0.5f, 0.f, -0.5f, -0.86602540f,
                                      -1.f,-0.86602540f,-0.5f, 0.f,  0.5f,  0.86602540f};
__device__ constexpr float TWS[12] = { 0.f,-0.5f,-0.86602540f,-1.f,-0.86602540f,-0.5f,
                                       0.f, 0.5f, 0.86602540f, 1.f, 0.86602540f, 0.5f};

__device__ constexpr float GW[11] = {0.00102838f, 0.00759876f, 0.03600076f, 0.10936070f,
                                     0.21300554f, 0.26601172f, 0.21300554f, 0.10936070f,
                                     0.03600076f, 0.00759876f, 0.00102838f};

// minimax atan poly, max err ~1e-6 rad (validated; rcp adds ~1ulp)
__device__ __forceinline__ float fast_atan2f(float y, float x) {
    float ax = fabsf(x), ay = fabsf(y);
    float mx = fmaxf(ax, ay), mn = fminf(ax, ay);
    float z = mn * __builtin_amdgcn_rcpf(mx);
    float z2 = z * z;
    float p = fmaf(z2, -0.01172120f, 0.05265332f);
    p = fmaf(z2, p, -0.11643287f);
    p = fmaf(z2, p, 0.19354346f);
    p = fmaf(z2, p, -0.33262347f);
    p = fmaf(z2, p, 0.99997726f);
    p = p * z;
    if (ay > ax) p = 1.57079632679489662f - p;
    if (x < 0.f) p = 3.14159265358979323f - p;
    return (y < 0.f) ? -p : p;
}

// swap the two halves of a __half2 (one v_alignbit_b32)
__device__ __forceinline__ __half2 h2swap(__half2 v) {
    unsigned u;
    __builtin_memcpy(&u, &v, 4);
    u = (u >> 16) | (u << 16);
    __half2 r;
    __builtin_memcpy(&r, &u, 4);
    return r;
}

// extract channel C of 4 consecutive NHWC pixels held in 3 float4s (wave-uniform c)
__device__ __forceinline__ float4 extract_c(float4 f0, float4 f1, float4 f2, int c) {
    if (c == 0) return make_float4(f0.x, f0.w, f1.z, f2.y);
    if (c == 1) return make_float4(f0.y, f1.x, f1.w, f2.z);
    return make_float4(f0.z, f1.y, f2.x, f2.w);
}

__global__ __launch_bounds__(THREADS) void work_kernel(const float* __restrict__ xin,
                                                       const float* __restrict__ xout,
                                                       const float* __restrict__ mean,
                                                       const float* __restrict__ logvar,
                                                       float* __restrict__ out) {
    __shared__ __align__(16) float SMEM[SMEM_FLOATS];
    __shared__ float sm8[8];
    const int tid = threadIdx.x;
    const int gid = blockIdx.x;
    float acc = 0.f;

    if (gid == 1824) {
        // ---- KLD block ----
        float a = 0.f;
        for (int i = tid; i < BATCH * LDIM; i += THREADS) {
            float m = mean[i], lv = logvar[i];
            a += -0.5f * (1.f + lv - expf(lv) - m * m) * (1.f / 32.f);
        }
        #pragma unroll
        for (int o = 32; o > 0; o >>= 1) a += __shfl_down(a, o, 64);
        if ((tid & 63) == 0) sm8[tid >> 6] = a;
        __syncthreads();
        if (tid == 0) {
            float s = sm8[0];
            #pragma unroll
            for (int i = 1; i < 8; ++i) s += sm8[i];
            atomicAdd(out, s);
        }
        return;
    }

    // fused work block: (b, c, tile); tile covers ssim rows 8t..8t+17, stft rows 8t..8t+15
    int b    = gid / 57;
    int rem  = gid % 57;
    int c    = rem / 19;
    int tile = rem % 19;
    int r0 = tile * 8;
    __half2* HXY = (__half2*)SMEM;                 // [rr 0..17][col] = (x, y)
    __half2* RD  = (__half2*)(SMEM + RD_OFF);      // stft scratch [r][vv][pc][re2,im2]
    const __half2 hz = __float2half2_rn(0.f);

    // ---- stage: 720 tasks (rr, colq); NHWC both imgs, extract c, pack half2 ----
    for (int t = tid; t < 720; t += THREADS) {
        int rr = t / 40;
        int cq = t % 40;
        int row = r0 + rr;
        float4 xa = make_float4(0.f, 0.f, 0.f, 0.f);
        float4 xb = make_float4(0.f, 0.f, 0.f, 0.f);
        if (row < NPIX) {
            size_t off = ((size_t)(b * 160 + row) * 160 + cq * 4) * 3;
            const float4* qa = (const float4*)(xin + off);
            const float4* qb = (const float4*)(xout + off);
            float4 a0 = qa[0], a1 = qa[1], a2 = qa[2];
            float4 b0 = qb[0], b1 = qb[1], b2 = qb[2];
            xa = extract_c(a0, a1, a2, c);
            xb = extract_c(b0, b1, b2, c);
        }
        __half2 h[4] __attribute__((aligned(16)));
        h[0] = __floats2half2_rn(xa.x, xb.x);
        h[1] = __floats2half2_rn(xa.y, xb.y);
        h[2] = __floats2half2_rn(xa.z, xb.z);
        h[3] = __floats2half2_rn(xa.w, xb.w);
        *(float4*)&HXY[rr * 160 + cq * 4] = *(float4*)h;
    }
    __syncthreads();

    // ---- stft phase A: 608 tasks (r 0..15, pc); packed-half DFT over BOTH imgs ----
    for (int t = tid; t < 608; t += THREADS) {
        int pc = t % 38;
        int r  = t / 38;
        float4 raw[3];
        raw[0] = *(const float4*)&HXY[r * 160 + pc * 4];
        raw[1] = *(const float4*)&HXY[r * 160 + pc * 4 + 4];
        raw[2] = *(const float4*)&HXY[r * 160 + pc * 4 + 8];
        const __half2* x = (const __half2*)raw;    // x[j] = (imgA, imgB)
        __half2 ev[5], ov[5];
        #pragma unroll
        for (int j = 1; j <= 5; ++j) {
            ev[j-1] = __hadd2(x[j], x[12 - j]);
            ov[j-1] = __hsub2(x[j], x[12 - j]);
        }
        #pragma unroll
        for (int vv = 0; vv < 5; ++vv) {
            const int v = vv + 1;
            __half2 re = (v & 1) ? __hsub2(x[0], x[6]) : __hadd2(x[0], x[6]);
            __half2 im = hz;
            #pragma unroll
            for (int j = 1; j <= 5; ++j) {
                const int kk = (v * j) % 12;       // compile-time
                re = __hfma2(ev[j-1], __float2half2_rn(TWC[kk]), re);
                im = __hfma2(ov[j-1], __float2half2_rn(TWS[kk]), im);
            }
            __half2 w2[2] __attribute__((aligned(8)));
            w2[0] = re;   // (reA, reB)
            w2[1] = im;   // (imA, imB)
            *(float2*)&RD[((r * 5 + vv) * 38 + pc) * 2] = *(float2*)w2;
        }
    }
    __syncthreads();

    // ---- stft phase B: 380 tasks (g, vv, pc); packed-half col-fold, fp32 epilogue ----
    if (tid < 380) {
        int pc = tid % 38;
        int vv = (tid / 38) % 5;
        int g  = tid / 190;
        __half2 FR[5], FI[5];
        #pragma unroll
        for (int uu = 0; uu < 5; ++uu) { FR[uu] = hz; FI[uu] = hz; }
        #pragma unroll
        for (int i = 0; i < 6; ++i) {
            int rlo = 4 * g + i, rhi = rlo + 6;
            __half2 lo[2] __attribute__((aligned(8)));
            __half2 hi[2] __attribute__((aligned(8)));
            *(float2*)lo = *(const float2*)&RD[((rlo * 5 + vv) * 38 + pc) * 2];
            *(float2*)hi = *(const float2*)&RD[((rhi * 5 + vv) * 38 + pc) * 2];
            __half2 spR = __hadd2(lo[0], hi[0]), smR = __hsub2(lo[0], hi[0]);
            __half2 spI = __hadd2(lo[1], hi[1]), smI = __hsub2(lo[1], hi[1]);
            #pragma unroll
            for (int uu = 0; uu < 5; ++uu) {
                const int u = uu + 1;
                const int kk = (u * i) % 12;       // compile-time twiddle
                __half2 sR = (u & 1) ? smR : spR;
                __half2 sI = (u & 1) ? smI : spI;
                // FR += c*sR - s*sI ; FI += c*sI + s*sR   (both imgs per lane)
                FR[uu] = __hfma2(sR, __float2half2_rn(TWC[kk]),
                         __hfma2(sI, __float2half2_rn(-TWS[kk]), FR[uu]));
                FI[uu] = __hfma2(sI, __float2half2_rn(TWC[kk]),
                         __hfma2(sR, __float2half2_rn(TWS[kk]), FI[uu]));
            }
        }
        float sacc = 0.f;
        #pragma unroll
        for (int uu = 0; uu < 5; ++uu) {
            float2 fr = __half22float2(FR[uu]);    // (A, B)
            float2 fi = __half22float2(FI[uu]);
            float aI = fast_atan2f(fi.x, fr.x + 1e-8f);
            float aO = fast_atan2f(fi.y, fr.y + 1e-8f);
            float mI = __builtin_amdgcn_sqrtf(fmaf(fr.x, fr.x, fi.x * fi.x));
            float mO = __builtin_amdgcn_sqrtf(fmaf(fr.y, fr.y, fi.y * fi.y));
            float ff = (float)((uu + 1) * (vv + 1)) * 0.04f;
            sacc += ff * (fabsf(aO - aI) + fabsf(mO - mI));
        }
        acc += sacc * (1e-4f / 32.f);
    }
    __syncthreads();   // RD dead; VP planes reuse the scratch region

    // ---- ssim phase V: vertical 11-tap, 320 tasks; packed-half accumulate ----
    for (int t = tid; t < 320; t += THREADS) {
        int orow = t / 40;
        int cbase = (t % 40) * 4;
        __half2 amu[4], avv[4], axy[4];
        #pragma unroll
        for (int o = 0; o < 4; ++o) { amu[o] = hz; avv[o] = hz; axy[o] = hz; }
        #pragma unroll
        for (int kk = 0; kk < 11; ++kk) {
            float4 raw = *(const float4*)&HXY[(orow + kk) * 160 + cbase];
            const __half2* h = (const __half2*)&raw;
            const __half2 w2 = __float2half2_rn(GW[kk]);   // compile-time
            #pragma unroll
            for (int o = 0; o < 4; ++o) {
                __half2 t2 = __hmul2(w2, h[o]);            // (w*x, w*y)
                amu[o] = __hadd2(amu[o], t2);              // (mu_x, mu_y)
                avv[o] = __hfma2(t2, h[o], avv[o]);        // (E[xx], E[yy])
                axy[o] = __hfma2(t2, h2swap(h[o]), axy[o]);// lo lane = w*x*y
            }
        }
        int base = orow * VROWSTR + cbase;
        *(float4*)&SMEM[VPMU_OFF + base] = *(float4*)amu;
        *(float4*)&SMEM[VPVV_OFF + base] = *(float4*)avv;
        *(float4*)&SMEM[VPXY_OFF + base] = make_float4(
            __low2float(axy[0]), __low2float(axy[1]),
            __low2float(axy[2]), __low2float(axy[3]));
    }
    __syncthreads();

    // ---- ssim phase H: 600 tasks (8 orows x 75 col-pairs); packed-half convs ----
    {
        float hacc = 0.f;
        for (int t = tid; t < 600; t += THREADS) {
            int orow = t / 75;
            int oc = (t % 75) * 2;
            int base = orow * VROWSTR + oc;
            // mu conv: both windows (oc, oc+1), both (x,y) lanes
            __half2 m[12], s0 = hz, s1 = hz;
            #pragma unroll
            for (int q = 0; q < 6; ++q)
                *(float2*)&m[2 * q] = *(const float2*)&SMEM[VPMU_OFF + base + 2 * q];
            #pragma unroll
            for (int kk = 0; kk < 11; ++kk) {
                const __half2 w2 = __float2half2_rn(GW[kk]);
                s0 = __hfma2(w2, m[kk],     s0);
                s1 = __hfma2(w2, m[kk + 1], s1);
            }
            float2 mu0 = __half22float2(s0);   // (mx, my) @ oc
            float2 mu1 = __half22float2(s1);   // (mx, my) @ oc+1
            // vv conv
            __half2 v0 = hz, v1 = hz;
            #pragma unroll
            for (int q = 0; q < 6; ++q)
                *(float2*)&m[2 * q] = *(const float2*)&SMEM[VPVV_OFF + base + 2 * q];
            #pragma unroll
            for (int kk = 0; kk < 11; ++kk) {
                const __half2 w2 = __float2half2_rn(GW[kk]);
                v0 = __hfma2(w2, m[kk],     v0);
                v1 = __hfma2(w2, m[kk + 1], v1);
            }
            float2 vv0 = __half22float2(v0);   // (E[xx], E[yy]) @ oc
            float2 vv1 = __half22float2(v1);
            // xy conv (fp32 plane)
            float zs[12];
            #pragma unroll
            for (int q = 0; q < 6; ++q) {
                float2 y2 = *(const float2*)&SMEM[VPXY_OFF + base + 2 * q];
                zs[2 * q] = y2.x; zs[2 * q + 1] = y2.y;
            }
            float xy0 = 0.f, xy1 = 0.f;
            #pragma unroll
            for (int kk = 0; kk < 11; ++kk) {
                xy0 = fmaf(GW[kk], zs[kk],     xy0);
                xy1 = fmaf(GW[kk], zs[kk + 1], xy1);
            }
            if (r0 + orow < OUT_SZ) {
                const float c1 = 1e-4f, c2 = 9e-4f;
                #pragma unroll
                for (int o = 0; o < 2; ++o) {
                    float mx = o ? mu1.x : mu0.x, my = o ? mu1.y : mu0.y;
                    float ex = o ? vv1.x : vv0.x, ey = o ? vv1.y : vv0.y;
                    float cv = (o ? xy1 : xy0) - mx * my;
                    float vx = ex - mx * mx;
                    float vy = ey - my * my;
                    float lum = (2.f * mx * my + c1) *
                                __builtin_amdgcn_rcpf(fmaf(mx, mx, my * my) + c1);
                    float cs  = (2.f * cv + c2) *
                                __builtin_amdgcn_rcpf(vx + vy + c2);
                    hacc += lum * cs;
                }
            }
        }
        acc += hacc * (1.f / (32.f * 150.f * 150.f * 3.f));
    }

    // ---- block reduce (8 waves) -> one device-scope atomic per block ----
    #pragma unroll
    for (int o = 32; o > 0; o >>= 1) acc += __shfl_down(acc, o, 64);
    if ((tid & 63) == 0) sm8[tid >> 6] = acc;
    __syncthreads();
    if (tid == 0) {
        float s = sm8[0];
        #pragma unroll
        for (int i = 1; i < 8; ++i) s += sm8[i];
        atomicAdd(out, s);
    }
}

extern "C" void kernel_launch(void* const* d_in, const int* in_sizes, int n_in,
                              void* d_out, int out_size, void* d_ws, size_t ws_size,
                              hipStream_t stream) {
    const float* mean   = (const float*)d_in[0];
    const float* logvar = (const float*)d_in[1];
    const float* xin    = (const float*)d_in[2];
    const float* xout   = (const float*)d_in[3];
    float* out = (float*)d_out;

    hipMemsetAsync(out, 0, sizeof(float), stream);   // graph-capturable memset node
    work_kernel<<<N_BLOCKS, THREADS, 0, stream>>>(xin, xout, mean, logvar, out);
}

// Round 5
// 105.190 us; speedup vs baseline: 1.1653x; 1.0001x over previous
//
#include <hip/hip_runtime.h>
#include <hip/hip_fp16.h>
#include <math.h>

#define BATCH 32
#define NPIX 160
#define LDIM 128
#define OUT_SZ 150        // 160 - 11 + 1

#define THREADS 512
// one fused block per (b, c, tile): 32*3*19 = 1824 work blocks + 1 KLD block
#define N_BLOCKS 1825
// LDS carve (float units; one __half2 = 4 B = ONE float slot):
//   HXY  [0,2880):  half2[18][160] staged pixels (x=img_in, y=img_out)
//   SCRATCH [2880,8960): union region, sequential use:
//     stft RD:  [r 0..15][pc 0..37][vv 0..4][re2,im2] = 16*38*10 = 6080 slots
//       (layout r,pc-major: per-(r,pc) 10 consecutive slots -> 40B lane stride
//        on pc => ~2-way banks, vs old [r][vv][pc] 304B stride => 8-way)
//     ssim VP:  VPMU half2[8][164] (mu_x,mu_y)      = 1312       (phases V,H)
//               VPVV half2[8][164] (E[xx],E[yy])    = 1312
//               VPXY float[8][164]  E[xy]           = 1312  (total 3936 <= 6080)
// 5-phase structure: stage -> A -> B -> V -> H; V overwrites RD after B.
#define RD_OFF   2880
#define VPMU_OFF 2880
#define VPVV_OFF 4192
#define VPXY_OFF 5504
#define VROWSTR  164
#define SMEM_FLOATS 8960   // 35.8 KB -> 4 blocks/CU (32 waves = full slots)

// e^{-i*2pi*k/12}; entries 0 / ±0.5 / ±0.866 / ±1
__device__ constexpr float TWC[12] = { 1.f, 0.86602540f, 0.5f, 0.f, -0.5f, -0.86602540f,
                                      -1.f,-0.86602540f,-0.5f, 0.f,  0.5f,  0.86602540f};
__device__ constexpr float TWS[12] = { 0.f,-0.5f,-0.86602540f,-1.f,-0.86602540f,-0.5f,
                                       0.f, 0.5f, 0.86602540f, 1.f, 0.86602540f, 0.5f};

__device__ constexpr float GW[11] = {0.00102838f, 0.00759876f, 0.03600076f, 0.10936070f,
                                     0.21300554f, 0.26601172f, 0.21300554f, 0.10936070f,
                                     0.03600076f, 0.00759876f, 0.00102838f};

// minimax atan poly, max err ~1e-6 rad (validated; rcp adds ~1ulp)
__device__ __forceinline__ float fast_atan2f(float y, float x) {
    float ax = fabsf(x), ay = fabsf(y);
    float mx = fmaxf(ax, ay), mn = fminf(ax, ay);
    float z = mn * __builtin_amdgcn_rcpf(mx);
    float z2 = z * z;
    float p = fmaf(z2, -0.01172120f, 0.05265332f);
    p = fmaf(z2, p, -0.11643287f);
    p = fmaf(z2, p, 0.19354346f);
    p = fmaf(z2, p, -0.33262347f);
    p = fmaf(z2, p, 0.99997726f);
    p = p * z;
    if (ay > ax) p = 1.57079632679489662f - p;
    if (x < 0.f) p = 3.14159265358979323f - p;
    return (y < 0.f) ? -p : p;
}

// swap the two halves of a __half2 (one v_alignbit_b32)
__device__ __forceinline__ __half2 h2swap(__half2 v) {
    unsigned u;
    __builtin_memcpy(&u, &v, 4);
    u = (u >> 16) | (u << 16);
    __half2 r;
    __builtin_memcpy(&r, &u, 4);
    return r;
}

// extract channel C of 4 consecutive NHWC pixels held in 3 float4s (wave-uniform c)
__device__ __forceinline__ float4 extract_c(float4 f0, float4 f1, float4 f2, int c) {
    if (c == 0) return make_float4(f0.x, f0.w, f1.z, f2.y);
    if (c == 1) return make_float4(f0.y, f1.x, f1.w, f2.z);
    return make_float4(f0.z, f1.y, f2.x, f2.w);
}

__global__ __launch_bounds__(THREADS) void work_kernel(const float* __restrict__ xin,
                                                       const float* __restrict__ xout,
                                                       const float* __restrict__ mean,
                                                       const float* __restrict__ logvar,
                                                       float* __restrict__ out) {
    __shared__ __align__(16) float SMEM[SMEM_FLOATS];
    __shared__ float sm8[8];
    const int tid = threadIdx.x;
    const int gid = blockIdx.x;
    float acc = 0.f;

    if (gid == 1824) {
        // ---- KLD block ----
        float a = 0.f;
        for (int i = tid; i < BATCH * LDIM; i += THREADS) {
            float m = mean[i], lv = logvar[i];
            a += -0.5f * (1.f + lv - expf(lv) - m * m) * (1.f / 32.f);
        }
        #pragma unroll
        for (int o = 32; o > 0; o >>= 1) a += __shfl_down(a, o, 64);
        if ((tid & 63) == 0) sm8[tid >> 6] = a;
        __syncthreads();
        if (tid == 0) {
            float s = sm8[0];
            #pragma unroll
            for (int i = 1; i < 8; ++i) s += sm8[i];
            atomicAdd(out, s);
        }
        return;
    }

    // XCD-aware decode: workgroups round-robin XCDs by gid%8, so give each XCD
    // a contiguous chunk of work items (1824 = 8*228). c fastest => the 3
    // channel-blocks of one (b,tile) run on the SAME XCD and share L2 lines
    // (staging float4 loads fetch all channels); consecutive tiles share
    // 10/18 staged rows for further L2 reuse.
    int idx  = (gid & 7) * 228 + (gid >> 3);
    int b    = idx / 57;
    int rem  = idx % 57;
    int tile = (rem / 3);
    int c    = rem % 3;
    int r0 = tile * 8;
    __half2* HXY = (__half2*)SMEM;                 // [rr 0..17][col] = (x, y)
    __half2* RD  = (__half2*)(SMEM + RD_OFF);      // stft scratch [r][pc][vv][re2,im2]
    const __half2 hz = __float2half2_rn(0.f);

    // ---- stage: 720 tasks (rr, colq); NHWC both imgs, extract c, pack half2 ----
    for (int t = tid; t < 720; t += THREADS) {
        int rr = t / 40;
        int cq = t % 40;
        int row = r0 + rr;
        float4 xa = make_float4(0.f, 0.f, 0.f, 0.f);
        float4 xb = make_float4(0.f, 0.f, 0.f, 0.f);
        if (row < NPIX) {
            size_t off = ((size_t)(b * 160 + row) * 160 + cq * 4) * 3;
            const float4* qa = (const float4*)(xin + off);
            const float4* qb = (const float4*)(xout + off);
            float4 a0 = qa[0], a1 = qa[1], a2 = qa[2];
            float4 b0 = qb[0], b1 = qb[1], b2 = qb[2];
            xa = extract_c(a0, a1, a2, c);
            xb = extract_c(b0, b1, b2, c);
        }
        __half2 h[4] __attribute__((aligned(16)));
        h[0] = __floats2half2_rn(xa.x, xb.x);
        h[1] = __floats2half2_rn(xa.y, xb.y);
        h[2] = __floats2half2_rn(xa.z, xb.z);
        h[3] = __floats2half2_rn(xa.w, xb.w);
        *(float4*)&HXY[rr * 160 + cq * 4] = *(float4*)h;
    }
    __syncthreads();

    // ---- stft phase A: 608 tasks (r 0..15, pc); packed-half DFT over BOTH imgs ----
    for (int t = tid; t < 608; t += THREADS) {
        int pc = t % 38;
        int r  = t / 38;
        float4 raw[3];
        raw[0] = *(const float4*)&HXY[r * 160 + pc * 4];
        raw[1] = *(const float4*)&HXY[r * 160 + pc * 4 + 4];
        raw[2] = *(const float4*)&HXY[r * 160 + pc * 4 + 8];
        const __half2* x = (const __half2*)raw;    // x[j] = (imgA, imgB)
        __half2 ev[5], ov[5];
        #pragma unroll
        for (int j = 1; j <= 5; ++j) {
            ev[j-1] = __hadd2(x[j], x[12 - j]);
            ov[j-1] = __hsub2(x[j], x[12 - j]);
        }
        __half2* dst = &RD[(r * 38 + pc) * 10];    // 10 consecutive slots
        #pragma unroll
        for (int vv = 0; vv < 5; ++vv) {
            const int v = vv + 1;
            __half2 re = (v & 1) ? __hsub2(x[0], x[6]) : __hadd2(x[0], x[6]);
            __half2 im = hz;
            #pragma unroll
            for (int j = 1; j <= 5; ++j) {
                const int kk = (v * j) % 12;       // compile-time
                re = __hfma2(ev[j-1], __float2half2_rn(TWC[kk]), re);
                im = __hfma2(ov[j-1], __float2half2_rn(TWS[kk]), im);
            }
            __half2 w2[2] __attribute__((aligned(8)));
            w2[0] = re;   // (reA, reB)
            w2[1] = im;   // (imA, imB)
            *(float2*)&dst[vv * 2] = *(float2*)w2;
        }
    }
    __syncthreads();

    // ---- stft phase B: 380 tasks (g, vv, pc); packed-half col-fold, fp32 epilogue ----
    if (tid < 380) {
        int pc = tid % 38;
        int vv = (tid / 38) % 5;
        int g  = tid / 190;
        __half2 FR[5], FI[5];
        #pragma unroll
        for (int uu = 0; uu < 5; ++uu) { FR[uu] = hz; FI[uu] = hz; }
        #pragma unroll
        for (int i = 0; i < 6; ++i) {
            int rlo = 4 * g + i, rhi = rlo + 6;
            __half2 lo[2] __attribute__((aligned(8)));
            __half2 hi[2] __attribute__((aligned(8)));
            *(float2*)lo = *(const float2*)&RD[(rlo * 38 + pc) * 10 + vv * 2];
            *(float2*)hi = *(const float2*)&RD[(rhi * 38 + pc) * 10 + vv * 2];
            __half2 spR = __hadd2(lo[0], hi[0]), smR = __hsub2(lo[0], hi[0]);
            __half2 spI = __hadd2(lo[1], hi[1]), smI = __hsub2(lo[1], hi[1]);
            #pragma unroll
            for (int uu = 0; uu < 5; ++uu) {
                const int u = uu + 1;
                const int kk = (u * i) % 12;       // compile-time twiddle
                __half2 sR = (u & 1) ? smR : spR;
                __half2 sI = (u & 1) ? smI : spI;
                // FR += c*sR - s*sI ; FI += c*sI + s*sR   (both imgs per lane)
                FR[uu] = __hfma2(sR, __float2half2_rn(TWC[kk]),
                         __hfma2(sI, __float2half2_rn(-TWS[kk]), FR[uu]));
                FI[uu] = __hfma2(sI, __float2half2_rn(TWC[kk]),
                         __hfma2(sR, __float2half2_rn(TWS[kk]), FI[uu]));
            }
        }
        float sacc = 0.f;
        #pragma unroll
        for (int uu = 0; uu < 5; ++uu) {
            float2 fr = __half22float2(FR[uu]);    // (A, B)
            float2 fi = __half22float2(FI[uu]);
            float aI = fast_atan2f(fi.x, fr.x + 1e-8f);
            float aO = fast_atan2f(fi.y, fr.y + 1e-8f);
            float mI = __builtin_amdgcn_sqrtf(fmaf(fr.x, fr.x, fi.x * fi.x));
            float mO = __builtin_amdgcn_sqrtf(fmaf(fr.y, fr.y, fi.y * fi.y));
            float ff = (float)((uu + 1) * (vv + 1)) * 0.04f;
            sacc += ff * (fabsf(aO - aI) + fabsf(mO - mI));
        }
        acc += sacc * (1e-4f / 32.f);
    }
    __syncthreads();   // RD dead; VP planes reuse the scratch region

    // ---- ssim phase V: vertical 11-tap, 320 tasks; packed-half accumulate ----
    for (int t = tid; t < 320; t += THREADS) {
        int orow = t / 40;
        int cbase = (t % 40) * 4;
        __half2 amu[4], avv[4], axy[4];
        #pragma unroll
        for (int o = 0; o < 4; ++o) { amu[o] = hz; avv[o] = hz; axy[o] = hz; }
        #pragma unroll
        for (int kk = 0; kk < 11; ++kk) {
            float4 raw = *(const float4*)&HXY[(orow + kk) * 160 + cbase];
            const __half2* h = (const __half2*)&raw;
            const __half2 w2 = __float2half2_rn(GW[kk]);   // compile-time
            #pragma unroll
            for (int o = 0; o < 4; ++o) {
                __half2 t2 = __hmul2(w2, h[o]);            // (w*x, w*y)
                amu[o] = __hadd2(amu[o], t2);              // (mu_x, mu_y)
                avv[o] = __hfma2(t2, h[o], avv[o]);        // (E[xx], E[yy])
                axy[o] = __hfma2(t2, h2swap(h[o]), axy[o]);// lo lane = w*x*y
            }
        }
        int base = orow * VROWSTR + cbase;
        *(float4*)&SMEM[VPMU_OFF + base] = *(float4*)amu;
        *(float4*)&SMEM[VPVV_OFF + base] = *(float4*)avv;
        *(float4*)&SMEM[VPXY_OFF + base] = make_float4(
            __low2float(axy[0]), __low2float(axy[1]),
            __low2float(axy[2]), __low2float(axy[3]));
    }
    __syncthreads();

    // ---- ssim phase H: 600 tasks (8 orows x 75 col-pairs); packed-half convs ----
    {
        float hacc = 0.f;
        for (int t = tid; t < 600; t += THREADS) {
            int orow = t / 75;
            int oc = (t % 75) * 2;
            int base = orow * VROWSTR + oc;
            // mu conv: both windows (oc, oc+1), both (x,y) lanes
            __half2 m[12], s0 = hz, s1 = hz;
            #pragma unroll
            for (int q = 0; q < 6; ++q)
                *(float2*)&m[2 * q] = *(const float2*)&SMEM[VPMU_OFF + base + 2 * q];
            #pragma unroll
            for (int kk = 0; kk < 11; ++kk) {
                const __half2 w2 = __float2half2_rn(GW[kk]);
                s0 = __hfma2(w2, m[kk],     s0);
                s1 = __hfma2(w2, m[kk + 1], s1);
            }
            float2 mu0 = __half22float2(s0);   // (mx, my) @ oc
            float2 mu1 = __half22float2(s1);   // (mx, my) @ oc+1
            // vv conv
            __half2 v0 = hz, v1 = hz;
            #pragma unroll
            for (int q = 0; q < 6; ++q)
                *(float2*)&m[2 * q] = *(const float2*)&SMEM[VPVV_OFF + base + 2 * q];
            #pragma unroll
            for (int kk = 0; kk < 11; ++kk) {
                const __half2 w2 = __float2half2_rn(GW[kk]);
                v0 = __hfma2(w2, m[kk],     v0);
                v1 = __hfma2(w2, m[kk + 1], v1);
            }
            float2 vv0 = __half22float2(v0);   // (E[xx], E[yy]) @ oc
            float2 vv1 = __half22float2(v1);
            // xy conv (fp32 plane)
            float zs[12];
            #pragma unroll
            for (int q = 0; q < 6; ++q) {
                float2 y2 = *(const float2*)&SMEM[VPXY_OFF + base + 2 * q];
                zs[2 * q] = y2.x; zs[2 * q + 1] = y2.y;
            }
            float xy0 = 0.f, xy1 = 0.f;
            #pragma unroll
            for (int kk = 0; kk < 11; ++kk) {
                xy0 = fmaf(GW[kk], zs[kk],     xy0);
                xy1 = fmaf(GW[kk], zs[kk + 1], xy1);
            }
            if (r0 + orow < OUT_SZ) {
                const float c1 = 1e-4f, c2 = 9e-4f;
                #pragma unroll
                for (int o = 0; o < 2; ++o) {
                    float mx = o ? mu1.x : mu0.x, my = o ? mu1.y : mu0.y;
                    float ex = o ? vv1.x : vv0.x, ey = o ? vv1.y : vv0.y;
                    float cv = (o ? xy1 : xy0) - mx * my;
                    float vx = ex - mx * mx;
                    float vy = ey - my * my;
                    float lum = (2.f * mx * my + c1) *
                                __builtin_amdgcn_rcpf(fmaf(mx, mx, my * my) + c1);
                    float cs  = (2.f * cv + c2) *
                                __builtin_amdgcn_rcpf(vx + vy + c2);
                    hacc += lum * cs;
                }
            }
        }
        acc += hacc * (1.f / (32.f * 150.f * 150.f * 3.f));
    }

    // ---- block reduce (8 waves) -> one device-scope atomic per block ----
    #pragma unroll
    for (int o = 32; o > 0; o >>= 1) acc += __shfl_down(acc, o, 64);
    if ((tid & 63) == 0) sm8[tid >> 6] = acc;
    __syncthreads();
    if (tid == 0) {
        float s = sm8[0];
        #pragma unroll
        for (int i = 1; i < 8; ++i) s += sm8[i];
        atomicAdd(out, s);
    }
}

extern "C" void kernel_launch(void* const* d_in, const int* in_sizes, int n_in,
                              void* d_out, int out_size, void* d_ws, size_t ws_size,
                              hipStream_t stream) {
    const float* mean   = (const float*)d_in[0];
    const float* logvar = (const float*)d_in[1];
    const float* xin    = (const float*)d_in[2];
    const float* xout   = (const float*)d_in[3];
    float* out = (float*)d_out;

    hipMemsetAsync(out, 0, sizeof(float), stream);   // graph-capturable memset node
    work_kernel<<<N_BLOCKS, THREADS, 0, stream>>>(xin, xout, mean, logvar, out);
}